// Round 2
// baseline (873.389 us; speedup 1.0000x reference)
//
#include <hip/hip_runtime.h>
#include <hip/hip_bf16.h>
#include <math.h>

#define T_TOK 2048
#define H_DIM 2048
#define I_DIM 1024
#define E_NUM 16
#define TOPK  4

#define BM 128
#define BN 128
#define BK 32

typedef __attribute__((ext_vector_type(8))) __bf16 bf16x8;
typedef __attribute__((ext_vector_type(4))) float  f32x4;

__device__ __forceinline__ unsigned short f2bf(float f) {
    unsigned int u = __builtin_bit_cast(unsigned int, f);
    unsigned int r = u + 0x7FFFu + ((u >> 16) & 1u);
    return (unsigned short)(r >> 16);
}

// async global->LDS DMA, 16 bytes per lane. LDS dest must be
// wave-uniform base + lane*16 (our staging layout is exactly linear in tid).
__device__ __forceinline__ void gload16(const void* g, void* l) {
    __builtin_amdgcn_global_load_lds(
        (const __attribute__((address_space(1))) unsigned int*)g,
        (__attribute__((address_space(3))) unsigned int*)l,
        16, 0, 0);
}

// ---------------- workspace layout (bytes) ----------------
static const size_t WS_COUNTS  = 0;
static const size_t WS_OFFSETS = 256;
static const size_t WS_TOK     = 512;
static const size_t WS_WL      = 131584;
static const size_t WS_X16     = 262656;
static const size_t WS_W1T     = 8651264;
static const size_t WS_W3T     = 75760128;
static const size_t WS_W2T     = 142868992;
static const size_t WS_ACT     = 209977856;

// ---------------- kernels ----------------

__global__ void zero_init(float* __restrict__ out, int* __restrict__ counts) {
    int i = blockIdx.x * blockDim.x + threadIdx.x;
    ((float4*)out)[i] = make_float4(0.f, 0.f, 0.f, 0.f);
    if (i < E_NUM) counts[i] = 0;
}

__global__ void convert_x(const float* __restrict__ x, unsigned short* __restrict__ X16) {
    int i = blockIdx.x * blockDim.x + threadIdx.x;
    float4 v = ((const float4*)x)[i];
    ushort4 o;
    o.x = f2bf(v.x); o.y = f2bf(v.y); o.z = f2bf(v.z); o.w = f2bf(v.w);
    ((ushort4*)X16)[i] = o;
}

// in: [E][R][C] fp32 -> out: [E][C][R] bf16
__global__ void transpose_conv(const float* __restrict__ in, unsigned short* __restrict__ out,
                               int R, int C) {
    __shared__ unsigned short tile[32][33];
    int e  = blockIdx.z;
    int c0 = blockIdx.x * 32;
    int r0 = blockIdx.y * 32;
    const float* ip = in + (size_t)e * R * C;
    unsigned short* op = out + (size_t)e * R * C;
    int t = threadIdx.x;            // 256 threads
    int r  = t >> 3;                // 0..31
    int c4 = (t & 7) * 4;           // 0,4,..28
    float4 v = *(const float4*)&ip[(size_t)(r0 + r) * C + c0 + c4];
    tile[c4 + 0][r] = f2bf(v.x);
    tile[c4 + 1][r] = f2bf(v.y);
    tile[c4 + 2][r] = f2bf(v.z);
    tile[c4 + 3][r] = f2bf(v.w);
    __syncthreads();
    ushort4 o;
    o.x = tile[r][c4 + 0];
    o.y = tile[r][c4 + 1];
    o.z = tile[r][c4 + 2];
    o.w = tile[r][c4 + 3];
    *(ushort4*)&op[(size_t)(c0 + r) * R + r0 + c4] = o;
}

__global__ void router(const float* __restrict__ x, const float* __restrict__ gw,
                       int* __restrict__ counts, int* __restrict__ tok,
                       float* __restrict__ wl) {
    int t = blockIdx.x;
    int lane = threadIdx.x;  // 64
    float acc[E_NUM];
#pragma unroll
    for (int e = 0; e < E_NUM; e++) acc[e] = 0.f;
    const float* xr = x + (size_t)t * H_DIM;
    for (int h = lane; h < H_DIM; h += 64) {
        float xv = xr[h];
#pragma unroll
        for (int e = 0; e < E_NUM; e++) acc[e] += xv * gw[e * H_DIM + h];
    }
#pragma unroll
    for (int e = 0; e < E_NUM; e++) {
#pragma unroll
        for (int off = 32; off; off >>= 1) acc[e] += __shfl_down(acc[e], off);
    }
    if (lane == 0) {
        bool used[E_NUM];
#pragma unroll
        for (int e = 0; e < E_NUM; e++) used[e] = false;
        int   idx[TOPK];
        float lv[TOPK];
        for (int k = 0; k < TOPK; k++) {
            float best = -1e30f; int bi = 0;
            for (int e = 0; e < E_NUM; e++)
                if (!used[e] && acc[e] > best) { best = acc[e]; bi = e; }
            used[bi] = true; idx[k] = bi; lv[k] = best;
        }
        float m = lv[0];
        float w[TOPK]; float s = 0.f;
        for (int k = 0; k < TOPK; k++) { w[k] = expf(lv[k] - m); s += w[k]; }
        float inv = 1.f / s;
        for (int k = 0; k < TOPK; k++) {
            int pos = atomicAdd(&counts[idx[k]], 1);
            tok[idx[k] * T_TOK + pos] = t;
            wl [idx[k] * T_TOK + pos] = w[k] * inv;
        }
    }
}

__global__ void prefix(const int* __restrict__ counts, int* __restrict__ offsets) {
    if (threadIdx.x == 0 && blockIdx.x == 0) {
        int s = 0;
        for (int e = 0; e < E_NUM; e++) { offsets[e] = s; s += counts[e]; }
    }
}

// stage1: act[slot][i] = silu(X@w1) * (X@w3) * route_weight,  bf16
// 2-phase double-buffered pipeline: issue tile t+1's global_load_lds, then
// ds_read+MFMA tile t, then ONE vmcnt(0)+s_barrier per K-step (T3 minimum).
__global__ __launch_bounds__(256, 3) void stage1(
    const unsigned short* __restrict__ X16,   // [T][H]
    const unsigned short* __restrict__ w1t,   // [E][I][H]
    const unsigned short* __restrict__ w3t,   // [E][I][H]
    const int* __restrict__ counts, const int* __restrict__ offsets,
    const int* __restrict__ tok, const float* __restrict__ wl,
    unsigned short* __restrict__ act)         // [8192][I]
{
    int e   = blockIdx.z;
    int n_e = counts[e];
    int m0  = blockIdx.y * BM;
    if (m0 >= n_e) return;
    int n0  = blockIdx.x * BN;

    __shared__ __align__(16) unsigned short As [2][BM][BK];
    __shared__ __align__(16) unsigned short B1s[2][BN][BK];
    __shared__ __align__(16) unsigned short B2s[2][BN][BK];

    int tid  = threadIdx.x;
    int wave = tid >> 6, lane = tid & 63;
    int wm = (wave >> 1) * 64, wn = (wave & 1) * 64;
    int lr = lane & 15, lq = lane >> 4;

    const unsigned short* w1p = w1t + (size_t)e * I_DIM * H_DIM;
    const unsigned short* w3p = w3t + (size_t)e * I_DIM * H_DIM;

    // per-thread staging coords (fixed across K): idx = rep*256+tid,
    // LDS byte offset = idx*16 -> linear in tid, as global_load_lds requires
    int ar[2]; int rr[2]; int cc[2];
#pragma unroll
    for (int rep = 0; rep < 2; rep++) {
        int idx = rep * 256 + tid;
        rr[rep] = idx >> 2;
        cc[rep] = (idx & 3) * 8;
        int gm = m0 + rr[rep];
        ar[rep] = tok[e * T_TOK + (gm < n_e ? gm : n_e - 1)];
    }

    auto stage = [&](int buf, int k0) {
#pragma unroll
        for (int rep = 0; rep < 2; rep++) {
            int r = rr[rep], ch = cc[rep];
            gload16(&X16[(size_t)ar[rep] * H_DIM + k0 + ch], &As [buf][r][ch]);
            gload16(&w1p[(size_t)(n0 + r) * H_DIM + k0 + ch], &B1s[buf][r][ch]);
            gload16(&w3p[(size_t)(n0 + r) * H_DIM + k0 + ch], &B2s[buf][r][ch]);
        }
    };

    f32x4 acc1[4][4] = {};
    f32x4 acc3[4][4] = {};

    const int NK = H_DIM / BK;   // 64
    stage(0, 0);
    asm volatile("s_waitcnt vmcnt(0)" ::: "memory");
    __builtin_amdgcn_s_barrier();

    for (int t = 0; t < NK; ++t) {
        int cur = t & 1;
        if (t + 1 < NK) stage(cur ^ 1, (t + 1) * BK);   // prefetch next tile
        bf16x8 af[4], b1f[4], b2f[4];
#pragma unroll
        for (int ti = 0; ti < 4; ti++)
            af[ti] = *(const bf16x8*)&As[cur][wm + ti * 16 + lr][lq * 8];
#pragma unroll
        for (int tj = 0; tj < 4; tj++) {
            b1f[tj] = *(const bf16x8*)&B1s[cur][wn + tj * 16 + lr][lq * 8];
            b2f[tj] = *(const bf16x8*)&B2s[cur][wn + tj * 16 + lr][lq * 8];
        }
#pragma unroll
        for (int ti = 0; ti < 4; ti++)
#pragma unroll
            for (int tj = 0; tj < 4; tj++) {
                acc1[ti][tj] = __builtin_amdgcn_mfma_f32_16x16x32_bf16(af[ti], b1f[tj], acc1[ti][tj], 0, 0, 0);
                acc3[ti][tj] = __builtin_amdgcn_mfma_f32_16x16x32_bf16(af[ti], b2f[tj], acc3[ti][tj], 0, 0, 0);
            }
        // one drain+barrier per K-step: prefetched loads had ds_read+MFMA to land
        asm volatile("s_waitcnt vmcnt(0)" ::: "memory");
        __builtin_amdgcn_s_barrier();
    }

    int slotbase = offsets[e] + m0;
#pragma unroll
    for (int ti = 0; ti < 4; ti++) {
#pragma unroll
        for (int reg = 0; reg < 4; reg++) {
            int mrow = wm + ti * 16 + lq * 4 + reg;
            int gm = m0 + mrow;
            if (gm >= n_e) continue;
            float wt = wl[e * T_TOK + gm];
            size_t obase = (size_t)(slotbase + mrow) * I_DIM + n0;
#pragma unroll
            for (int tj = 0; tj < 4; tj++) {
                float h1 = acc1[ti][tj][reg];
                float h3 = acc3[ti][tj][reg];
                float a = (h1 / (1.f + expf(-h1))) * h3 * wt;
                act[obase + wn + tj * 16 + lr] = f2bf(a);
            }
        }
    }
}

// stage2: out[tok] += act @ w2   (same 2-phase pipeline)
__global__ __launch_bounds__(256, 3) void stage2(
    const unsigned short* __restrict__ act,   // [8192][I]
    const unsigned short* __restrict__ w2t,   // [E][H][I]
    const int* __restrict__ counts, const int* __restrict__ offsets,
    const int* __restrict__ tok,
    float* __restrict__ out)                  // [T][H]
{
    int e   = blockIdx.z;
    int n_e = counts[e];
    int m0  = blockIdx.y * BM;
    if (m0 >= n_e) return;
    int n0  = blockIdx.x * BN;   // over H

    __shared__ __align__(16) unsigned short As[2][BM][BK];
    __shared__ __align__(16) unsigned short Bs[2][BN][BK];

    int tid  = threadIdx.x;
    int wave = tid >> 6, lane = tid & 63;
    int wm = (wave >> 1) * 64, wn = (wave & 1) * 64;
    int lr = lane & 15, lq = lane >> 4;

    const unsigned short* w2p = w2t + (size_t)e * H_DIM * I_DIM;
    int slotbase = offsets[e];

    int rr[2]; int cc[2]; int arow[2];
#pragma unroll
    for (int rep = 0; rep < 2; rep++) {
        int idx = rep * 256 + tid;
        rr[rep] = idx >> 2;
        cc[rep] = (idx & 3) * 8;
        int gm = m0 + rr[rep];
        arow[rep] = slotbase + (gm < n_e ? gm : n_e - 1);
    }

    auto stage = [&](int buf, int k0) {
#pragma unroll
        for (int rep = 0; rep < 2; rep++) {
            int r = rr[rep], ch = cc[rep];
            gload16(&act[(size_t)arow[rep] * I_DIM + k0 + ch], &As[buf][r][ch]);
            gload16(&w2p[(size_t)(n0 + r) * I_DIM + k0 + ch], &Bs[buf][r][ch]);
        }
    };

    f32x4 acc[4][4] = {};

    const int NK = I_DIM / BK;   // 32
    stage(0, 0);
    asm volatile("s_waitcnt vmcnt(0)" ::: "memory");
    __builtin_amdgcn_s_barrier();

    for (int t = 0; t < NK; ++t) {
        int cur = t & 1;
        if (t + 1 < NK) stage(cur ^ 1, (t + 1) * BK);
        bf16x8 af[4], bf[4];
#pragma unroll
        for (int ti = 0; ti < 4; ti++)
            af[ti] = *(const bf16x8*)&As[cur][wm + ti * 16 + lr][lq * 8];
#pragma unroll
        for (int tj = 0; tj < 4; tj++)
            bf[tj] = *(const bf16x8*)&Bs[cur][wn + tj * 16 + lr][lq * 8];
#pragma unroll
        for (int ti = 0; ti < 4; ti++)
#pragma unroll
            for (int tj = 0; tj < 4; tj++)
                acc[ti][tj] = __builtin_amdgcn_mfma_f32_16x16x32_bf16(af[ti], bf[tj], acc[ti][tj], 0, 0, 0);
        asm volatile("s_waitcnt vmcnt(0)" ::: "memory");
        __builtin_amdgcn_s_barrier();
    }

#pragma unroll
    for (int ti = 0; ti < 4; ti++) {
#pragma unroll
        for (int reg = 0; reg < 4; reg++) {
            int mrow = wm + ti * 16 + lq * 4 + reg;
            int gm = m0 + mrow;
            if (gm >= n_e) continue;
            int tm = tok[e * T_TOK + gm];
            size_t obase = (size_t)tm * H_DIM + n0;
#pragma unroll
            for (int tj = 0; tj < 4; tj++)
                atomicAdd(&out[obase + wn + tj * 16 + lr], acc[ti][tj][reg]);
        }
    }
}

// ---------------- launch ----------------
extern "C" void kernel_launch(void* const* d_in, const int* in_sizes, int n_in,
                              void* d_out, int out_size, void* d_ws, size_t ws_size,
                              hipStream_t stream) {
    const float* x_f32 = (const float*)d_in[0];
    const float* gw    = (const float*)d_in[1];
    const float* w1    = (const float*)d_in[2];
    const float* w3    = (const float*)d_in[3];
    const float* w2    = (const float*)d_in[4];
    float* out = (float*)d_out;

    char* ws = (char*)d_ws;
    int*            counts  = (int*)(ws + WS_COUNTS);
    int*            offsets = (int*)(ws + WS_OFFSETS);
    int*            tok     = (int*)(ws + WS_TOK);
    float*          wl      = (float*)(ws + WS_WL);
    unsigned short* X16     = (unsigned short*)(ws + WS_X16);
    unsigned short* w1t     = (unsigned short*)(ws + WS_W1T);
    unsigned short* w3t     = (unsigned short*)(ws + WS_W3T);
    unsigned short* w2t     = (unsigned short*)(ws + WS_W2T);
    unsigned short* act     = (unsigned short*)(ws + WS_ACT);

    zero_init<<<dim3((T_TOK * H_DIM / 4) / 256), 256, 0, stream>>>(out, counts);
    convert_x<<<dim3((T_TOK * H_DIM / 4) / 256), 256, 0, stream>>>(x_f32, X16);
    transpose_conv<<<dim3(I_DIM / 32, H_DIM / 32, E_NUM), 256, 0, stream>>>(w1, w1t, H_DIM, I_DIM);
    transpose_conv<<<dim3(I_DIM / 32, H_DIM / 32, E_NUM), 256, 0, stream>>>(w3, w3t, H_DIM, I_DIM);
    transpose_conv<<<dim3(H_DIM / 32, I_DIM / 32, E_NUM), 256, 0, stream>>>(w2, w2t, I_DIM, H_DIM);
    router<<<dim3(T_TOK), 64, 0, stream>>>(x_f32, gw, counts, tok, wl);
    prefix<<<dim3(1), 64, 0, stream>>>(counts, offsets);
    stage1<<<dim3(I_DIM / BN, T_TOK / BM, E_NUM), 256, 0, stream>>>(
        X16, w1t, w3t, counts, offsets, tok, wl, act);
    stage2<<<dim3(H_DIM / BN, T_TOK / BM, E_NUM), 256, 0, stream>>>(
        act, w2t, counts, offsets, tok, out);
}

// Round 3
// 813.511 us; speedup vs baseline: 1.0736x; 1.0736x over previous
//
#include <hip/hip_runtime.h>
#include <hip/hip_bf16.h>
#include <math.h>

#define T_TOK 2048
#define H_DIM 2048
#define I_DIM 1024
#define E_NUM 16
#define TOPK  4

#define BM 128
#define BN 128
#define BK 32

typedef __attribute__((ext_vector_type(8))) __bf16 bf16x8;
typedef __attribute__((ext_vector_type(4))) float  f32x4;

__device__ __forceinline__ unsigned short f2bf(float f) {
    unsigned int u = __builtin_bit_cast(unsigned int, f);
    unsigned int r = u + 0x7FFFu + ((u >> 16) & 1u);
    return (unsigned short)(r >> 16);
}

// async global->LDS DMA, 16 bytes per lane. LDS dest must be
// wave-uniform base + lane*16 (our staging layout is exactly linear in tid).
__device__ __forceinline__ void gload16(const void* g, void* l) {
    __builtin_amdgcn_global_load_lds(
        (const __attribute__((address_space(1))) unsigned int*)g,
        (__attribute__((address_space(3))) unsigned int*)l,
        16, 0, 0);
}

// ---------------- workspace layout (bytes) ----------------
static const size_t WS_COUNTS  = 0;
static const size_t WS_OFFSETS = 256;
static const size_t WS_TOK     = 512;
static const size_t WS_WL      = 131584;
static const size_t WS_X16     = 262656;
static const size_t WS_W1T     = 8651264;
static const size_t WS_W3T     = 75760128;
static const size_t WS_W2T     = 142868992;
static const size_t WS_ACT     = 209977856;

// ---------------- kernels ----------------

__global__ void zero_init(float* __restrict__ out, int* __restrict__ counts) {
    int i = blockIdx.x * blockDim.x + threadIdx.x;
    ((float4*)out)[i] = make_float4(0.f, 0.f, 0.f, 0.f);
    if (i < E_NUM) counts[i] = 0;
}

__global__ void convert_x(const float* __restrict__ x, unsigned short* __restrict__ X16) {
    int i = blockIdx.x * blockDim.x + threadIdx.x;
    float4 v = ((const float4*)x)[i];
    ushort4 o;
    o.x = f2bf(v.x); o.y = f2bf(v.y); o.z = f2bf(v.z); o.w = f2bf(v.w);
    ((ushort4*)X16)[i] = o;
}

// in: [E][R][C] fp32 -> out: [E][C][R] bf16
__global__ void transpose_conv(const float* __restrict__ in, unsigned short* __restrict__ out,
                               int R, int C) {
    __shared__ unsigned short tile[32][33];
    int e  = blockIdx.z;
    int c0 = blockIdx.x * 32;
    int r0 = blockIdx.y * 32;
    const float* ip = in + (size_t)e * R * C;
    unsigned short* op = out + (size_t)e * R * C;
    int t = threadIdx.x;            // 256 threads
    int r  = t >> 3;                // 0..31
    int c4 = (t & 7) * 4;           // 0,4,..28
    float4 v = *(const float4*)&ip[(size_t)(r0 + r) * C + c0 + c4];
    tile[c4 + 0][r] = f2bf(v.x);
    tile[c4 + 1][r] = f2bf(v.y);
    tile[c4 + 2][r] = f2bf(v.z);
    tile[c4 + 3][r] = f2bf(v.w);
    __syncthreads();
    ushort4 o;
    o.x = tile[r][c4 + 0];
    o.y = tile[r][c4 + 1];
    o.z = tile[r][c4 + 2];
    o.w = tile[r][c4 + 3];
    *(ushort4*)&op[(size_t)(c0 + r) * R + r0 + c4] = o;
}

__global__ void router(const float* __restrict__ x, const float* __restrict__ gw,
                       int* __restrict__ counts, int* __restrict__ tok,
                       float* __restrict__ wl) {
    int t = blockIdx.x;
    int lane = threadIdx.x;  // 64
    float acc[E_NUM];
#pragma unroll
    for (int e = 0; e < E_NUM; e++) acc[e] = 0.f;
    const float* xr = x + (size_t)t * H_DIM;
    for (int h = lane; h < H_DIM; h += 64) {
        float xv = xr[h];
#pragma unroll
        for (int e = 0; e < E_NUM; e++) acc[e] += xv * gw[e * H_DIM + h];
    }
#pragma unroll
    for (int e = 0; e < E_NUM; e++) {
#pragma unroll
        for (int off = 32; off; off >>= 1) acc[e] += __shfl_down(acc[e], off);
    }
    if (lane == 0) {
        bool used[E_NUM];
#pragma unroll
        for (int e = 0; e < E_NUM; e++) used[e] = false;
        int   idx[TOPK];
        float lv[TOPK];
        for (int k = 0; k < TOPK; k++) {
            float best = -1e30f; int bi = 0;
            for (int e = 0; e < E_NUM; e++)
                if (!used[e] && acc[e] > best) { best = acc[e]; bi = e; }
            used[bi] = true; idx[k] = bi; lv[k] = best;
        }
        float m = lv[0];
        float w[TOPK]; float s = 0.f;
        for (int k = 0; k < TOPK; k++) { w[k] = expf(lv[k] - m); s += w[k]; }
        float inv = 1.f / s;
        for (int k = 0; k < TOPK; k++) {
            int pos = atomicAdd(&counts[idx[k]], 1);
            tok[idx[k] * T_TOK + pos] = t;
            wl [idx[k] * T_TOK + pos] = w[k] * inv;
        }
    }
}

__global__ void prefix(const int* __restrict__ counts, int* __restrict__ offsets) {
    if (threadIdx.x == 0 && blockIdx.x == 0) {
        int s = 0;
        for (int e = 0; e < E_NUM; e++) { offsets[e] = s; s += counts[e]; }
    }
}

// stage1: act[slot][i] = silu(X@w1) * (X@w3) * route_weight,  bf16
// Depth-2 pipeline: 3 LDS buffers; per K-step wait vmcnt(6) (tile t complete,
// t+1/t+2 stay in flight), raw s_barrier, issue tile t+2, compute tile t.
// vmcnt never drains to 0 in the main loop (T4). launch_bounds min-waves=2:
// min=3 caps VGPR below the 128-reg accumulators -> spills (round-2 regression).
__global__ __launch_bounds__(256, 2) void stage1(
    const unsigned short* __restrict__ X16,   // [T][H]
    const unsigned short* __restrict__ w1t,   // [E][I][H]
    const unsigned short* __restrict__ w3t,   // [E][I][H]
    const int* __restrict__ counts, const int* __restrict__ offsets,
    const int* __restrict__ tok, const float* __restrict__ wl,
    unsigned short* __restrict__ act)         // [8192][I]
{
    int e   = blockIdx.z;
    int n_e = counts[e];
    int m0  = blockIdx.y * BM;
    if (m0 >= n_e) return;
    int n0  = blockIdx.x * BN;

    __shared__ __align__(16) unsigned short As [3][BM][BK];
    __shared__ __align__(16) unsigned short B1s[3][BN][BK];
    __shared__ __align__(16) unsigned short B2s[3][BN][BK];

    int tid  = threadIdx.x;
    int wave = tid >> 6, lane = tid & 63;
    int wm = (wave >> 1) * 64, wn = (wave & 1) * 64;
    int lr = lane & 15, lq = lane >> 4;

    const unsigned short* w1p = w1t + (size_t)e * I_DIM * H_DIM;
    const unsigned short* w3p = w3t + (size_t)e * I_DIM * H_DIM;

    // per-thread staging coords (fixed across K): idx = rep*256+tid,
    // LDS byte offset = idx*16 -> linear in tid, as global_load_lds requires
    int ar[2]; int rr[2]; int cc[2];
#pragma unroll
    for (int rep = 0; rep < 2; rep++) {
        int idx = rep * 256 + tid;
        rr[rep] = idx >> 2;
        cc[rep] = (idx & 3) * 8;
        int gm = m0 + rr[rep];
        ar[rep] = tok[e * T_TOK + (gm < n_e ? gm : n_e - 1)];
    }

    auto stage = [&](int buf, int k0) {   // 6 gload_lds instrs per wave
#pragma unroll
        for (int rep = 0; rep < 2; rep++) {
            int r = rr[rep], ch = cc[rep];
            gload16(&X16[(size_t)ar[rep] * H_DIM + k0 + ch], &As [buf][r][ch]);
            gload16(&w1p[(size_t)(n0 + r) * H_DIM + k0 + ch], &B1s[buf][r][ch]);
            gload16(&w3p[(size_t)(n0 + r) * H_DIM + k0 + ch], &B2s[buf][r][ch]);
        }
    };

    f32x4 acc1[4][4] = {};
    f32x4 acc3[4][4] = {};

    const int NK = H_DIM / BK;   // 64
    stage(0, 0);
    stage(1, BK);

    int cur = 0;
    for (int t = 0; t < NK; ++t) {
        if (t < NK - 1) asm volatile("s_waitcnt vmcnt(6)" ::: "memory");
        else            asm volatile("s_waitcnt vmcnt(0)" ::: "memory");
        __builtin_amdgcn_s_barrier();
        if (t + 2 < NK) {
            int nb = cur + 2; if (nb >= 3) nb -= 3;
            stage(nb, (t + 2) * BK);
        }
        bf16x8 af[4], b1f[4], b2f[4];
#pragma unroll
        for (int ti = 0; ti < 4; ti++)
            af[ti] = *(const bf16x8*)&As[cur][wm + ti * 16 + lr][lq * 8];
#pragma unroll
        for (int tj = 0; tj < 4; tj++) {
            b1f[tj] = *(const bf16x8*)&B1s[cur][wn + tj * 16 + lr][lq * 8];
            b2f[tj] = *(const bf16x8*)&B2s[cur][wn + tj * 16 + lr][lq * 8];
        }
#pragma unroll
        for (int ti = 0; ti < 4; ti++)
#pragma unroll
            for (int tj = 0; tj < 4; tj++) {
                acc1[ti][tj] = __builtin_amdgcn_mfma_f32_16x16x32_bf16(af[ti], b1f[tj], acc1[ti][tj], 0, 0, 0);
                acc3[ti][tj] = __builtin_amdgcn_mfma_f32_16x16x32_bf16(af[ti], b2f[tj], acc3[ti][tj], 0, 0, 0);
            }
        cur = cur + 1 == 3 ? 0 : cur + 1;
    }

    int slotbase = offsets[e] + m0;
#pragma unroll
    for (int ti = 0; ti < 4; ti++) {
#pragma unroll
        for (int reg = 0; reg < 4; reg++) {
            int mrow = wm + ti * 16 + lq * 4 + reg;
            int gm = m0 + mrow;
            if (gm >= n_e) continue;
            float wt = wl[e * T_TOK + gm];
            size_t obase = (size_t)(slotbase + mrow) * I_DIM + n0;
#pragma unroll
            for (int tj = 0; tj < 4; tj++) {
                float h1 = acc1[ti][tj][reg];
                float h3 = acc3[ti][tj][reg];
                float a = (h1 / (1.f + expf(-h1))) * h3 * wt;
                act[obase + wn + tj * 16 + lr] = f2bf(a);
            }
        }
    }
}

// stage2: out[tok] += act @ w2   (same depth-2 pipeline, vmcnt(4))
__global__ __launch_bounds__(256, 2) void stage2(
    const unsigned short* __restrict__ act,   // [8192][I]
    const unsigned short* __restrict__ w2t,   // [E][H][I]
    const int* __restrict__ counts, const int* __restrict__ offsets,
    const int* __restrict__ tok,
    float* __restrict__ out)                  // [T][H]
{
    int e   = blockIdx.z;
    int n_e = counts[e];
    int m0  = blockIdx.y * BM;
    if (m0 >= n_e) return;
    int n0  = blockIdx.x * BN;   // over H

    __shared__ __align__(16) unsigned short As[3][BM][BK];
    __shared__ __align__(16) unsigned short Bs[3][BN][BK];

    int tid  = threadIdx.x;
    int wave = tid >> 6, lane = tid & 63;
    int wm = (wave >> 1) * 64, wn = (wave & 1) * 64;
    int lr = lane & 15, lq = lane >> 4;

    const unsigned short* w2p = w2t + (size_t)e * H_DIM * I_DIM;
    int slotbase = offsets[e];

    int rr[2]; int cc[2]; int arow[2];
#pragma unroll
    for (int rep = 0; rep < 2; rep++) {
        int idx = rep * 256 + tid;
        rr[rep] = idx >> 2;
        cc[rep] = (idx & 3) * 8;
        int gm = m0 + rr[rep];
        arow[rep] = slotbase + (gm < n_e ? gm : n_e - 1);
    }

    auto stage = [&](int buf, int k0) {   // 4 gload_lds instrs per wave
#pragma unroll
        for (int rep = 0; rep < 2; rep++) {
            int r = rr[rep], ch = cc[rep];
            gload16(&act[(size_t)arow[rep] * I_DIM + k0 + ch], &As[buf][r][ch]);
            gload16(&w2p[(size_t)(n0 + r) * I_DIM + k0 + ch], &Bs[buf][r][ch]);
        }
    };

    f32x4 acc[4][4] = {};

    const int NK = I_DIM / BK;   // 32
    stage(0, 0);
    stage(1, BK);

    int cur = 0;
    for (int t = 0; t < NK; ++t) {
        if (t < NK - 1) asm volatile("s_waitcnt vmcnt(4)" ::: "memory");
        else            asm volatile("s_waitcnt vmcnt(0)" ::: "memory");
        __builtin_amdgcn_s_barrier();
        if (t + 2 < NK) {
            int nb = cur + 2; if (nb >= 3) nb -= 3;
            stage(nb, (t + 2) * BK);
        }
        bf16x8 af[4], bf[4];
#pragma unroll
        for (int ti = 0; ti < 4; ti++)
            af[ti] = *(const bf16x8*)&As[cur][wm + ti * 16 + lr][lq * 8];
#pragma unroll
        for (int tj = 0; tj < 4; tj++)
            bf[tj] = *(const bf16x8*)&Bs[cur][wn + tj * 16 + lr][lq * 8];
#pragma unroll
        for (int ti = 0; ti < 4; ti++)
#pragma unroll
            for (int tj = 0; tj < 4; tj++)
                acc[ti][tj] = __builtin_amdgcn_mfma_f32_16x16x32_bf16(af[ti], bf[tj], acc[ti][tj], 0, 0, 0);
        cur = cur + 1 == 3 ? 0 : cur + 1;
    }

#pragma unroll
    for (int ti = 0; ti < 4; ti++) {
#pragma unroll
        for (int reg = 0; reg < 4; reg++) {
            int mrow = wm + ti * 16 + lq * 4 + reg;
            int gm = m0 + mrow;
            if (gm >= n_e) continue;
            int tm = tok[e * T_TOK + gm];
            size_t obase = (size_t)tm * H_DIM + n0;
#pragma unroll
            for (int tj = 0; tj < 4; tj++)
                atomicAdd(&out[obase + wn + tj * 16 + lr], acc[ti][tj][reg]);
        }
    }
}

// ---------------- launch ----------------
extern "C" void kernel_launch(void* const* d_in, const int* in_sizes, int n_in,
                              void* d_out, int out_size, void* d_ws, size_t ws_size,
                              hipStream_t stream) {
    const float* x_f32 = (const float*)d_in[0];
    const float* gw    = (const float*)d_in[1];
    const float* w1    = (const float*)d_in[2];
    const float* w3    = (const float*)d_in[3];
    const float* w2    = (const float*)d_in[4];
    float* out = (float*)d_out;

    char* ws = (char*)d_ws;
    int*            counts  = (int*)(ws + WS_COUNTS);
    int*            offsets = (int*)(ws + WS_OFFSETS);
    int*            tok     = (int*)(ws + WS_TOK);
    float*          wl      = (float*)(ws + WS_WL);
    unsigned short* X16     = (unsigned short*)(ws + WS_X16);
    unsigned short* w1t     = (unsigned short*)(ws + WS_W1T);
    unsigned short* w3t     = (unsigned short*)(ws + WS_W3T);
    unsigned short* w2t     = (unsigned short*)(ws + WS_W2T);
    unsigned short* act     = (unsigned short*)(ws + WS_ACT);

    zero_init<<<dim3((T_TOK * H_DIM / 4) / 256), 256, 0, stream>>>(out, counts);
    convert_x<<<dim3((T_TOK * H_DIM / 4) / 256), 256, 0, stream>>>(x_f32, X16);
    transpose_conv<<<dim3(I_DIM / 32, H_DIM / 32, E_NUM), 256, 0, stream>>>(w1, w1t, H_DIM, I_DIM);
    transpose_conv<<<dim3(I_DIM / 32, H_DIM / 32, E_NUM), 256, 0, stream>>>(w3, w3t, H_DIM, I_DIM);
    transpose_conv<<<dim3(H_DIM / 32, I_DIM / 32, E_NUM), 256, 0, stream>>>(w2, w2t, I_DIM, H_DIM);
    router<<<dim3(T_TOK), 64, 0, stream>>>(x_f32, gw, counts, tok, wl);
    prefix<<<dim3(1), 64, 0, stream>>>(counts, offsets);
    stage1<<<dim3(I_DIM / BN, T_TOK / BM, E_NUM), 256, 0, stream>>>(
        X16, w1t, w3t, counts, offsets, tok, wl, act);
    stage2<<<dim3(H_DIM / BN, T_TOK / BM, E_NUM), 256, 0, stream>>>(
        act, w2t, counts, offsets, tok, out);
}

// Round 8
// 790.057 us; speedup vs baseline: 1.1055x; 1.0297x over previous
//
#include <hip/hip_runtime.h>
#include <hip/hip_bf16.h>
#include <math.h>

#define T_TOK 2048
#define H_DIM 2048
#define I_DIM 1024
#define E_NUM 16
#define TOPK  4

#define BM 128
#define BN 128
#define BK 32
#define MAXMB 80   // max compact m-blocks: sum ceil(cnt_e/BM) <= 8192/128 + 15 = 79

typedef __attribute__((ext_vector_type(8))) __bf16 bf16x8;
typedef __attribute__((ext_vector_type(4))) float  f32x4;

__device__ __forceinline__ unsigned short f2bf(float f) {
    unsigned int u = __builtin_bit_cast(unsigned int, f);
    unsigned int r = u + 0x7FFFu + ((u >> 16) & 1u);
    return (unsigned short)(r >> 16);
}

// async global->LDS DMA, 16 bytes per lane. LDS dest must be
// wave-uniform base + lane*16 (our staging layout is exactly linear in tid).
__device__ __forceinline__ void gload16(const void* g, void* l) {
    __builtin_amdgcn_global_load_lds(
        (const __attribute__((address_space(1))) unsigned int*)g,
        (__attribute__((address_space(3))) unsigned int*)l,
        16, 0, 0);
}

// ---------------- workspace layout (bytes) ----------------
// counts ints 0..15 @0; work-list ushort[96] @64 (rewritten by prefix each iter)
// offsets ints 0..16 @256; nmb @ offsets[17]
static const size_t WS_COUNTS  = 0;
static const size_t WS_WORK    = 64;
static const size_t WS_OFFSETS = 256;
static const size_t WS_TOK     = 512;
static const size_t WS_WL      = 131584;
static const size_t WS_X16     = 262656;
static const size_t WS_W1T     = 8651264;
static const size_t WS_W3T     = 75760128;
static const size_t WS_W2T     = 142868992;
static const size_t WS_ACT     = 209977856;

// ---------------- kernels ----------------

__global__ void zero_init(float* __restrict__ out, int* __restrict__ counts) {
    int i = blockIdx.x * blockDim.x + threadIdx.x;
    ((float4*)out)[i] = make_float4(0.f, 0.f, 0.f, 0.f);
    if (i < E_NUM) counts[i] = 0;
}

__global__ void convert_x(const float* __restrict__ x, unsigned short* __restrict__ X16) {
    int i = blockIdx.x * blockDim.x + threadIdx.x;
    float4 v = ((const float4*)x)[i];
    ushort4 o;
    o.x = f2bf(v.x); o.y = f2bf(v.y); o.z = f2bf(v.z); o.w = f2bf(v.w);
    ((ushort4*)X16)[i] = o;
}

// in: [E][R][C] fp32 -> out: [E][C][R] bf16
__global__ void transpose_conv(const float* __restrict__ in, unsigned short* __restrict__ out,
                               int R, int C) {
    __shared__ unsigned short tile[32][33];
    int e  = blockIdx.z;
    int c0 = blockIdx.x * 32;
    int r0 = blockIdx.y * 32;
    const float* ip = in + (size_t)e * R * C;
    unsigned short* op = out + (size_t)e * R * C;
    int t = threadIdx.x;            // 256 threads
    int r  = t >> 3;                // 0..31
    int c4 = (t & 7) * 4;           // 0,4,..28
    float4 v = *(const float4*)&ip[(size_t)(r0 + r) * C + c0 + c4];
    tile[c4 + 0][r] = f2bf(v.x);
    tile[c4 + 1][r] = f2bf(v.y);
    tile[c4 + 2][r] = f2bf(v.z);
    tile[c4 + 3][r] = f2bf(v.w);
    __syncthreads();
    ushort4 o;
    o.x = tile[r][c4 + 0];
    o.y = tile[r][c4 + 1];
    o.z = tile[r][c4 + 2];
    o.w = tile[r][c4 + 3];
    *(ushort4*)&op[(size_t)(c0 + r) * R + r0 + c4] = o;
}

__global__ void router(const float* __restrict__ x, const float* __restrict__ gw,
                       int* __restrict__ counts, int* __restrict__ tok,
                       float* __restrict__ wl) {
    int t = blockIdx.x;
    int lane = threadIdx.x;  // 64
    float acc[E_NUM];
#pragma unroll
    for (int e = 0; e < E_NUM; e++) acc[e] = 0.f;
    const float* xr = x + (size_t)t * H_DIM;
    for (int h = lane; h < H_DIM; h += 64) {
        float xv = xr[h];
#pragma unroll
        for (int e = 0; e < E_NUM; e++) acc[e] += xv * gw[e * H_DIM + h];
    }
#pragma unroll
    for (int e = 0; e < E_NUM; e++) {
#pragma unroll
        for (int off = 32; off; off >>= 1) acc[e] += __shfl_down(acc[e], off);
    }
    if (lane == 0) {
        bool used[E_NUM];
#pragma unroll
        for (int e = 0; e < E_NUM; e++) used[e] = false;
        int   idx[TOPK];
        float lv[TOPK];
        for (int k = 0; k < TOPK; k++) {
            float best = -1e30f; int bi = 0;
            for (int e = 0; e < E_NUM; e++)
                if (!used[e] && acc[e] > best) { best = acc[e]; bi = e; }
            used[bi] = true; idx[k] = bi; lv[k] = best;
        }
        float m = lv[0];
        float w[TOPK]; float s = 0.f;
        for (int k = 0; k < TOPK; k++) { w[k] = expf(lv[k] - m); s += w[k]; }
        float inv = 1.f / s;
        for (int k = 0; k < TOPK; k++) {
            int pos = atomicAdd(&counts[idx[k]], 1);
            tok[idx[k] * T_TOK + pos] = t;
            wl [idx[k] * T_TOK + pos] = w[k] * inv;
        }
    }
}

// offsets[0..16] = exclusive prefix (+ total at [16]); offsets[17] = nmb;
// work[j] = (e<<8)|mblock  -- compact list of active (expert, m-tile) pairs
__global__ void prefix(const int* __restrict__ counts, int* __restrict__ offsets,
                       unsigned short* __restrict__ work) {
    if (threadIdx.x == 0 && blockIdx.x == 0) {
        int c[E_NUM]; int s = 0;
        for (int e = 0; e < E_NUM; e++) { c[e] = counts[e]; offsets[e] = s; s += c[e]; }
        offsets[E_NUM] = s;
        int n = 0;
        for (int e = 0; e < E_NUM; e++) {
            int mb = (c[e] + BM - 1) / BM;
            for (int m = 0; m < mb; m++) work[n++] = (unsigned short)((e << 8) | m);
        }
        offsets[E_NUM + 1] = n;
    }
}

// stage1: act[slot][i] = silu(X@w1) * (X@w3) * route_weight,  bf16
// Round-1 proven inner loop (single LDS buffer, gload_lds, __syncthreads),
// grid compacted via work-list so every launched block is active ->
// even 2-3 blocks/CU placement gives block-level latency overlap.
__global__ __launch_bounds__(256, 2) void stage1(
    const unsigned short* __restrict__ X16,   // [T][H]
    const unsigned short* __restrict__ w1t,   // [E][I][H]
    const unsigned short* __restrict__ w3t,   // [E][I][H]
    const int* __restrict__ offsets, const unsigned short* __restrict__ work,
    const int* __restrict__ tok, const float* __restrict__ wl,
    unsigned short* __restrict__ act)         // [8192][I]
{
    int j = blockIdx.y;
    if (j >= offsets[E_NUM + 1]) return;
    int ent = work[j];
    int e   = ent >> 8;
    int m0  = (ent & 255) * BM;
    int n_e = offsets[e + 1] - offsets[e];
    int n0  = blockIdx.x * BN;

    __shared__ __align__(16) unsigned short As [BM][BK];
    __shared__ __align__(16) unsigned short B1s[BN][BK];
    __shared__ __align__(16) unsigned short B2s[BN][BK];

    int tid  = threadIdx.x;
    int wave = tid >> 6, lane = tid & 63;
    int wm = (wave >> 1) * 64, wn = (wave & 1) * 64;
    int lr = lane & 15, lq = lane >> 4;

    const unsigned short* w1p = w1t + (size_t)e * I_DIM * H_DIM;
    const unsigned short* w3p = w3t + (size_t)e * I_DIM * H_DIM;

    // per-thread staging coords (fixed across K): idx = rep*256+tid,
    // LDS byte offset = idx*16 -> linear in tid, as global_load_lds requires
    int ar[2]; int rr[2]; int cc[2];
#pragma unroll
    for (int rep = 0; rep < 2; rep++) {
        int idx = rep * 256 + tid;
        rr[rep] = idx >> 2;
        cc[rep] = (idx & 3) * 8;
        int gm = m0 + rr[rep];
        ar[rep] = tok[e * T_TOK + (gm < n_e ? gm : n_e - 1)];
    }

    f32x4 acc1[4][4] = {};
    f32x4 acc3[4][4] = {};

    for (int k0 = 0; k0 < H_DIM; k0 += BK) {
#pragma unroll
        for (int rep = 0; rep < 2; rep++) {
            int r = rr[rep], ch = cc[rep];
            gload16(&X16[(size_t)ar[rep] * H_DIM + k0 + ch], &As [r][ch]);
            gload16(&w1p[(size_t)(n0 + r) * H_DIM + k0 + ch], &B1s[r][ch]);
            gload16(&w3p[(size_t)(n0 + r) * H_DIM + k0 + ch], &B2s[r][ch]);
        }
        __syncthreads();   // drains vmcnt(0) -> LDS tiles ready
        bf16x8 af[4], b1f[4], b2f[4];
#pragma unroll
        for (int ti = 0; ti < 4; ti++)
            af[ti] = *(const bf16x8*)&As[wm + ti * 16 + lr][lq * 8];
#pragma unroll
        for (int tj = 0; tj < 4; tj++) {
            b1f[tj] = *(const bf16x8*)&B1s[wn + tj * 16 + lr][lq * 8];
            b2f[tj] = *(const bf16x8*)&B2s[wn + tj * 16 + lr][lq * 8];
        }
#pragma unroll
        for (int ti = 0; ti < 4; ti++)
#pragma unroll
            for (int tj = 0; tj < 4; tj++) {
                acc1[ti][tj] = __builtin_amdgcn_mfma_f32_16x16x32_bf16(af[ti], b1f[tj], acc1[ti][tj], 0, 0, 0);
                acc3[ti][tj] = __builtin_amdgcn_mfma_f32_16x16x32_bf16(af[ti], b2f[tj], acc3[ti][tj], 0, 0, 0);
            }
        __syncthreads();
    }

    int slotbase = offsets[e] + m0;
#pragma unroll
    for (int ti = 0; ti < 4; ti++) {
#pragma unroll
        for (int reg = 0; reg < 4; reg++) {
            int mrow = wm + ti * 16 + lq * 4 + reg;
            int gm = m0 + mrow;
            if (gm >= n_e) continue;
            float wt = wl[e * T_TOK + gm];
            size_t obase = (size_t)(slotbase + mrow) * I_DIM + n0;
#pragma unroll
            for (int tj = 0; tj < 4; tj++) {
                float h1 = acc1[ti][tj][reg];
                float h3 = acc3[ti][tj][reg];
                float a = (h1 / (1.f + expf(-h1))) * h3 * wt;
                act[obase + wn + tj * 16 + lr] = f2bf(a);
            }
        }
    }
}

// stage2: out[tok] += act @ w2   (same compacted mapping)
__global__ __launch_bounds__(256, 2) void stage2(
    const unsigned short* __restrict__ act,   // [8192][I]
    const unsigned short* __restrict__ w2t,   // [E][H][I]
    const int* __restrict__ offsets, const unsigned short* __restrict__ work,
    const int* __restrict__ tok,
    float* __restrict__ out)                  // [T][H]
{
    int j = blockIdx.y;
    if (j >= offsets[E_NUM + 1]) return;
    int ent = work[j];
    int e   = ent >> 8;
    int m0  = (ent & 255) * BM;
    int n_e = offsets[e + 1] - offsets[e];
    int n0  = blockIdx.x * BN;   // over H

    __shared__ __align__(16) unsigned short As[BM][BK];
    __shared__ __align__(16) unsigned short Bs[BN][BK];

    int tid  = threadIdx.x;
    int wave = tid >> 6, lane = tid & 63;
    int wm = (wave >> 1) * 64, wn = (wave & 1) * 64;
    int lr = lane & 15, lq = lane >> 4;

    const unsigned short* w2p = w2t + (size_t)e * H_DIM * I_DIM;
    int slotbase = offsets[e];

    int rr[2]; int cc[2]; int arow[2];
#pragma unroll
    for (int rep = 0; rep < 2; rep++) {
        int idx = rep * 256 + tid;
        rr[rep] = idx >> 2;
        cc[rep] = (idx & 3) * 8;
        int gm = m0 + rr[rep];
        arow[rep] = slotbase + (gm < n_e ? gm : n_e - 1);
    }

    f32x4 acc[4][4] = {};

    for (int k0 = 0; k0 < I_DIM; k0 += BK) {
#pragma unroll
        for (int rep = 0; rep < 2; rep++) {
            int r = rr[rep], ch = cc[rep];
            gload16(&act[(size_t)arow[rep] * I_DIM + k0 + ch], &As[r][ch]);
            gload16(&w2p[(size_t)(n0 + r) * I_DIM + k0 + ch], &Bs[r][ch]);
        }
        __syncthreads();
        bf16x8 af[4], bf[4];
#pragma unroll
        for (int ti = 0; ti < 4; ti++)
            af[ti] = *(const bf16x8*)&As[wm + ti * 16 + lr][lq * 8];
#pragma unroll
        for (int tj = 0; tj < 4; tj++)
            bf[tj] = *(const bf16x8*)&Bs[wn + tj * 16 + lr][lq * 8];
#pragma unroll
        for (int ti = 0; ti < 4; ti++)
#pragma unroll
            for (int tj = 0; tj < 4; tj++)
                acc[ti][tj] = __builtin_amdgcn_mfma_f32_16x16x32_bf16(af[ti], bf[tj], acc[ti][tj], 0, 0, 0);
        __syncthreads();
    }

#pragma unroll
    for (int ti = 0; ti < 4; ti++) {
#pragma unroll
        for (int reg = 0; reg < 4; reg++) {
            int mrow = wm + ti * 16 + lq * 4 + reg;
            int gm = m0 + mrow;
            if (gm >= n_e) continue;
            int tm = tok[e * T_TOK + gm];
            size_t obase = (size_t)tm * H_DIM + n0;
#pragma unroll
            for (int tj = 0; tj < 4; tj++)
                atomicAdd(&out[obase + wn + tj * 16 + lr], acc[ti][tj][reg]);
        }
    }
}

// ---------------- launch ----------------
extern "C" void kernel_launch(void* const* d_in, const int* in_sizes, int n_in,
                              void* d_out, int out_size, void* d_ws, size_t ws_size,
                              hipStream_t stream) {
    const float* x_f32 = (const float*)d_in[0];
    const float* gw    = (const float*)d_in[1];
    const float* w1    = (const float*)d_in[2];
    const float* w3    = (const float*)d_in[3];
    const float* w2    = (const float*)d_in[4];
    float* out = (float*)d_out;

    char* ws = (char*)d_ws;
    int*            counts  = (int*)(ws + WS_COUNTS);
    unsigned short* work    = (unsigned short*)(ws + WS_WORK);
    int*            offsets = (int*)(ws + WS_OFFSETS);
    int*            tok     = (int*)(ws + WS_TOK);
    float*          wl      = (float*)(ws + WS_WL);
    unsigned short* X16     = (unsigned short*)(ws + WS_X16);
    unsigned short* w1t     = (unsigned short*)(ws + WS_W1T);
    unsigned short* w3t     = (unsigned short*)(ws + WS_W3T);
    unsigned short* w2t     = (unsigned short*)(ws + WS_W2T);
    unsigned short* act     = (unsigned short*)(ws + WS_ACT);

    zero_init<<<dim3((T_TOK * H_DIM / 4) / 256), 256, 0, stream>>>(out, counts);
    convert_x<<<dim3((T_TOK * H_DIM / 4) / 256), 256, 0, stream>>>(x_f32, X16);
    transpose_conv<<<dim3(I_DIM / 32, H_DIM / 32, E_NUM), 256, 0, stream>>>(w1, w1t, H_DIM, I_DIM);
    transpose_conv<<<dim3(I_DIM / 32, H_DIM / 32, E_NUM), 256, 0, stream>>>(w3, w3t, H_DIM, I_DIM);
    transpose_conv<<<dim3(H_DIM / 32, I_DIM / 32, E_NUM), 256, 0, stream>>>(w2, w2t, I_DIM, H_DIM);
    router<<<dim3(T_TOK), 64, 0, stream>>>(x_f32, gw, counts, tok, wl);
    prefix<<<dim3(1), 64, 0, stream>>>(counts, offsets, work);
    // compacted grids: y indexes the work-list (<= MAXMB entries, tiny dead tail)
    stage1<<<dim3(I_DIM / BN, MAXMB), 256, 0, stream>>>(
        X16, w1t, w3t, offsets, work, tok, wl, act);
    stage2<<<dim3(H_DIM / BN, MAXMB), 256, 0, stream>>>(
        act, w2t, offsets, work, tok, out);
}

// Round 9
// 767.653 us; speedup vs baseline: 1.1377x; 1.0292x over previous
//
#include <hip/hip_runtime.h>
#include <hip/hip_bf16.h>
#include <math.h>

#define T_TOK 2048
#define H_DIM 2048
#define I_DIM 1024
#define E_NUM 16
#define TOPK  4

#define BM 128
#define BN 128
#define BK 32
#define MAXMB 80   // max compact m-blocks: sum ceil(cnt_e/BM) <= 8192/128 + 15 = 79

typedef __attribute__((ext_vector_type(8))) __bf16 bf16x8;
typedef __attribute__((ext_vector_type(4))) float  f32x4;
typedef __attribute__((ext_vector_type(8))) unsigned short u16x8;

__device__ __forceinline__ unsigned short f2bf(float f) {
    unsigned int u = __builtin_bit_cast(unsigned int, f);
    unsigned int r = u + 0x7FFFu + ((u >> 16) & 1u);
    return (unsigned short)(r >> 16);
}

// async global->LDS DMA, 16 bytes per lane. LDS dest must be
// wave-uniform base + lane*16 (our staging layout is exactly linear in tid).
__device__ __forceinline__ void gload16(const void* g, void* l) {
    __builtin_amdgcn_global_load_lds(
        (const __attribute__((address_space(1))) unsigned int*)g,
        (__attribute__((address_space(3))) unsigned int*)l,
        16, 0, 0);
}

// ---------------- workspace layout (bytes) ----------------
// h2s (stage2 dense output, f32 [8192][H]) REUSES the w1t region: w1t is
// dead after stage1's last read, stage2 writes it stream-ordered after.
static const size_t WS_COUNTS  = 0;
static const size_t WS_WORK    = 64;
static const size_t WS_OFFSETS = 256;
static const size_t WS_TOK     = 512;
static const size_t WS_WL      = 131584;
static const size_t WS_X16     = 262656;
static const size_t WS_W1T     = 8651264;
static const size_t WS_H2S     = 8651264;    // alias of w1t region (64MB, exact fit)
static const size_t WS_W3T     = 75760128;
static const size_t WS_W2T     = 142868992;
static const size_t WS_ACT     = 209977856;
static const size_t WS_POSMAP  = 226755072;  // int[T][4] = 32KB

// ---------------- kernels ----------------

__global__ void zero_counts(int* __restrict__ counts) {
    if (threadIdx.x < E_NUM) counts[threadIdx.x] = 0;
}

__global__ void convert_x(const float* __restrict__ x, unsigned short* __restrict__ X16) {
    int i = blockIdx.x * blockDim.x + threadIdx.x;
    float4 v = ((const float4*)x)[i];
    ushort4 o;
    o.x = f2bf(v.x); o.y = f2bf(v.y); o.z = f2bf(v.z); o.w = f2bf(v.w);
    ((ushort4*)X16)[i] = o;
}

// in: [E][R][C] fp32 -> out: [E][C][R] bf16.  64x64 tiles; writes are
// 16B/lane (u16x8) so an 8-lane group covers a 128B contiguous segment.
__global__ void transpose_conv(const float* __restrict__ in, unsigned short* __restrict__ out,
                               int R, int C) {
    __shared__ unsigned short tile[64][68];   // pad 68: 136B row stride (8B-aligned, ~4-way wr conflict)
    int e  = blockIdx.z;
    int c0 = blockIdx.x * 64;
    int r0 = blockIdx.y * 64;
    const float* ip = in + (size_t)e * R * C;
    unsigned short* op = out + (size_t)e * R * C;
    int t  = threadIdx.x;           // 256 threads
    int rr = t >> 4;                // 0..15
    int c4 = (t & 15) * 4;          // 0,4,..60
#pragma unroll
    for (int p = 0; p < 4; p++) {
        int r = p * 16 + rr;
        float4 v = *(const float4*)&ip[(size_t)(r0 + r) * C + c0 + c4];
        tile[c4 + 0][r] = f2bf(v.x);
        tile[c4 + 1][r] = f2bf(v.y);
        tile[c4 + 2][r] = f2bf(v.z);
        tile[c4 + 3][r] = f2bf(v.w);
    }
    __syncthreads();
    int cc = t >> 3;                // 0..31
    int r8 = (t & 7) * 8;           // 0,8,..56
#pragma unroll
    for (int p = 0; p < 2; p++) {
        int c = p * 32 + cc;
        union { u16x8 v8; ushort4 v4[2]; } u;
        u.v4[0] = *(const ushort4*)&tile[c][r8];
        u.v4[1] = *(const ushort4*)&tile[c][r8 + 4];
        *(u16x8*)&op[(size_t)(c0 + c) * R + r0 + r8] = u.v8;
    }
}

__global__ void router(const float* __restrict__ x, const float* __restrict__ gw,
                       int* __restrict__ counts, int* __restrict__ tok,
                       float* __restrict__ wl, int* __restrict__ posmap) {
    int t = blockIdx.x;
    int lane = threadIdx.x;  // 64
    float acc[E_NUM];
#pragma unroll
    for (int e = 0; e < E_NUM; e++) acc[e] = 0.f;
    const float* xr = x + (size_t)t * H_DIM;
    for (int h = lane; h < H_DIM; h += 64) {
        float xv = xr[h];
#pragma unroll
        for (int e = 0; e < E_NUM; e++) acc[e] += xv * gw[e * H_DIM + h];
    }
#pragma unroll
    for (int e = 0; e < E_NUM; e++) {
#pragma unroll
        for (int off = 32; off; off >>= 1) acc[e] += __shfl_down(acc[e], off);
    }
    if (lane == 0) {
        bool used[E_NUM];
#pragma unroll
        for (int e = 0; e < E_NUM; e++) used[e] = false;
        int   idx[TOPK];
        float lv[TOPK];
        for (int k = 0; k < TOPK; k++) {
            float best = -1e30f; int bi = 0;
            for (int e = 0; e < E_NUM; e++)
                if (!used[e] && acc[e] > best) { best = acc[e]; bi = e; }
            used[bi] = true; idx[k] = bi; lv[k] = best;
        }
        float m = lv[0];
        float w[TOPK]; float s = 0.f;
        for (int k = 0; k < TOPK; k++) { w[k] = expf(lv[k] - m); s += w[k]; }
        float inv = 1.f / s;
        for (int k = 0; k < TOPK; k++) {
            int pos = atomicAdd(&counts[idx[k]], 1);
            tok[idx[k] * T_TOK + pos] = t;
            wl [idx[k] * T_TOK + pos] = w[k] * inv;
            posmap[t * TOPK + k] = (idx[k] << 16) | pos;   // token -> (expert,pos)
        }
    }
}

// offsets[0..16] = exclusive prefix (+ total at [16]); offsets[17] = nmb;
// work[j] = (e<<8)|mblock  -- compact list of active (expert, m-tile) pairs
__global__ void prefix(const int* __restrict__ counts, int* __restrict__ offsets,
                       unsigned short* __restrict__ work) {
    if (threadIdx.x == 0 && blockIdx.x == 0) {
        int c[E_NUM]; int s = 0;
        for (int e = 0; e < E_NUM; e++) { c[e] = counts[e]; offsets[e] = s; s += c[e]; }
        offsets[E_NUM] = s;
        int n = 0;
        for (int e = 0; e < E_NUM; e++) {
            int mb = (c[e] + BM - 1) / BM;
            for (int m = 0; m < mb; m++) work[n++] = (unsigned short)((e << 8) | m);
        }
        offsets[E_NUM + 1] = n;
    }
}

// stage1: act[slot][i] = silu(X@w1) * (X@w3) * route_weight,  bf16
// UNCHANGED from round 8 (measured control: ~175us, MfmaUtil ~17%).
__global__ __launch_bounds__(256, 2) void stage1(
    const unsigned short* __restrict__ X16,   // [T][H]
    const unsigned short* __restrict__ w1t,   // [E][I][H]
    const unsigned short* __restrict__ w3t,   // [E][I][H]
    const int* __restrict__ offsets, const unsigned short* __restrict__ work,
    const int* __restrict__ tok, const float* __restrict__ wl,
    unsigned short* __restrict__ act)         // [8192][I]
{
    int j = blockIdx.y;
    if (j >= offsets[E_NUM + 1]) return;
    int ent = work[j];
    int e   = ent >> 8;
    int m0  = (ent & 255) * BM;
    int n_e = offsets[e + 1] - offsets[e];
    int n0  = blockIdx.x * BN;

    __shared__ __align__(16) unsigned short As [BM][BK];
    __shared__ __align__(16) unsigned short B1s[BN][BK];
    __shared__ __align__(16) unsigned short B2s[BN][BK];

    int tid  = threadIdx.x;
    int wave = tid >> 6, lane = tid & 63;
    int wm = (wave >> 1) * 64, wn = (wave & 1) * 64;
    int lr = lane & 15, lq = lane >> 4;

    const unsigned short* w1p = w1t + (size_t)e * I_DIM * H_DIM;
    const unsigned short* w3p = w3t + (size_t)e * I_DIM * H_DIM;

    int ar[2]; int rr[2]; int cc[2];
#pragma unroll
    for (int rep = 0; rep < 2; rep++) {
        int idx = rep * 256 + tid;
        rr[rep] = idx >> 2;
        cc[rep] = (idx & 3) * 8;
        int gm = m0 + rr[rep];
        ar[rep] = tok[e * T_TOK + (gm < n_e ? gm : n_e - 1)];
    }

    f32x4 acc1[4][4] = {};
    f32x4 acc3[4][4] = {};

    for (int k0 = 0; k0 < H_DIM; k0 += BK) {
#pragma unroll
        for (int rep = 0; rep < 2; rep++) {
            int r = rr[rep], ch = cc[rep];
            gload16(&X16[(size_t)ar[rep] * H_DIM + k0 + ch], &As [r][ch]);
            gload16(&w1p[(size_t)(n0 + r) * H_DIM + k0 + ch], &B1s[r][ch]);
            gload16(&w3p[(size_t)(n0 + r) * H_DIM + k0 + ch], &B2s[r][ch]);
        }
        __syncthreads();
        bf16x8 af[4], b1f[4], b2f[4];
#pragma unroll
        for (int ti = 0; ti < 4; ti++)
            af[ti] = *(const bf16x8*)&As[wm + ti * 16 + lr][lq * 8];
#pragma unroll
        for (int tj = 0; tj < 4; tj++) {
            b1f[tj] = *(const bf16x8*)&B1s[wn + tj * 16 + lr][lq * 8];
            b2f[tj] = *(const bf16x8*)&B2s[wn + tj * 16 + lr][lq * 8];
        }
#pragma unroll
        for (int ti = 0; ti < 4; ti++)
#pragma unroll
            for (int tj = 0; tj < 4; tj++) {
                acc1[ti][tj] = __builtin_amdgcn_mfma_f32_16x16x32_bf16(af[ti], b1f[tj], acc1[ti][tj], 0, 0, 0);
                acc3[ti][tj] = __builtin_amdgcn_mfma_f32_16x16x32_bf16(af[ti], b2f[tj], acc3[ti][tj], 0, 0, 0);
            }
        __syncthreads();
    }

    int slotbase = offsets[e] + m0;
#pragma unroll
    for (int ti = 0; ti < 4; ti++) {
#pragma unroll
        for (int reg = 0; reg < 4; reg++) {
            int mrow = wm + ti * 16 + lq * 4 + reg;
            int gm = m0 + mrow;
            if (gm >= n_e) continue;
            float wt = wl[e * T_TOK + gm];
            size_t obase = (size_t)(slotbase + mrow) * I_DIM + n0;
#pragma unroll
            for (int tj = 0; tj < 4; tj++) {
                float h1 = acc1[ti][tj][reg];
                float h3 = acc3[ti][tj][reg];
                float a = (h1 / (1.f + expf(-h1))) * h3 * wt;
                act[obase + wn + tj * 16 + lr] = f2bf(a);
            }
        }
    }
}

// stage2: h2s[slot][h] = act[slot] @ w2  -- DENSE slot-major f32 store,
// no atomics. Token scatter/sum moved to the combine kernel.
__global__ __launch_bounds__(256, 2) void stage2(
    const unsigned short* __restrict__ act,   // [8192][I]
    const unsigned short* __restrict__ w2t,   // [E][H][I]
    const int* __restrict__ offsets, const unsigned short* __restrict__ work,
    float* __restrict__ h2s)                  // [8192][H]
{
    int j = blockIdx.y;
    if (j >= offsets[E_NUM + 1]) return;
    int ent = work[j];
    int e   = ent >> 8;
    int m0  = (ent & 255) * BM;
    int n_e = offsets[e + 1] - offsets[e];
    int n0  = blockIdx.x * BN;   // over H

    __shared__ __align__(16) unsigned short As[BM][BK];
    __shared__ __align__(16) unsigned short Bs[BN][BK];

    int tid  = threadIdx.x;
    int wave = tid >> 6, lane = tid & 63;
    int wm = (wave >> 1) * 64, wn = (wave & 1) * 64;
    int lr = lane & 15, lq = lane >> 4;

    const unsigned short* w2p = w2t + (size_t)e * H_DIM * I_DIM;
    int slotbase = offsets[e];

    int rr[2]; int cc[2]; int arow[2];
#pragma unroll
    for (int rep = 0; rep < 2; rep++) {
        int idx = rep * 256 + tid;
        rr[rep] = idx >> 2;
        cc[rep] = (idx & 3) * 8;
        int gm = m0 + rr[rep];
        arow[rep] = slotbase + (gm < n_e ? gm : n_e - 1);
    }

    f32x4 acc[4][4] = {};

    for (int k0 = 0; k0 < I_DIM; k0 += BK) {
#pragma unroll
        for (int rep = 0; rep < 2; rep++) {
            int r = rr[rep], ch = cc[rep];
            gload16(&act[(size_t)arow[rep] * I_DIM + k0 + ch], &As[r][ch]);
            gload16(&w2p[(size_t)(n0 + r) * I_DIM + k0 + ch], &Bs[r][ch]);
        }
        __syncthreads();
        bf16x8 af[4], bf[4];
#pragma unroll
        for (int ti = 0; ti < 4; ti++)
            af[ti] = *(const bf16x8*)&As[wm + ti * 16 + lr][lq * 8];
#pragma unroll
        for (int tj = 0; tj < 4; tj++)
            bf[tj] = *(const bf16x8*)&Bs[wn + tj * 16 + lr][lq * 8];
#pragma unroll
        for (int ti = 0; ti < 4; ti++)
#pragma unroll
            for (int tj = 0; tj < 4; tj++)
                acc[ti][tj] = __builtin_amdgcn_mfma_f32_16x16x32_bf16(af[ti], bf[tj], acc[ti][tj], 0, 0, 0);
        __syncthreads();
    }

#pragma unroll
    for (int ti = 0; ti < 4; ti++) {
#pragma unroll
        for (int reg = 0; reg < 4; reg++) {
            int mrow = wm + ti * 16 + lq * 4 + reg;
            int gm = m0 + mrow;
            if (gm >= n_e) continue;
            size_t obase = (size_t)(slotbase + gm) * H_DIM + n0;
#pragma unroll
            for (int tj = 0; tj < 4; tj++)
                h2s[obase + wn + tj * 16 + lr] = acc[ti][tj][reg];
        }
    }
}

// combine: out[t][h] = sum_k h2s[slot(t,k)][h]  -- pure BW gather, no atomics
__global__ void combine(const float* __restrict__ h2s, const int* __restrict__ posmap,
                        const int* __restrict__ offsets, float* __restrict__ out) {
    int t   = blockIdx.x;
    int idx = blockIdx.y * 256 + threadIdx.x;      // 0..511 -> float4 over H=2048
    int slot[TOPK];
#pragma unroll
    for (int k = 0; k < TOPK; k++) {
        int pm = posmap[t * TOPK + k];
        slot[k] = offsets[pm >> 16] + (pm & 0xffff);
    }
    float4 s = make_float4(0.f, 0.f, 0.f, 0.f);
#pragma unroll
    for (int k = 0; k < TOPK; k++) {
        float4 v = *(const float4*)&h2s[(size_t)slot[k] * H_DIM + idx * 4];
        s.x += v.x; s.y += v.y; s.z += v.z; s.w += v.w;
    }
    *(float4*)&out[(size_t)t * H_DIM + idx * 4] = s;
}

// ---------------- launch ----------------
extern "C" void kernel_launch(void* const* d_in, const int* in_sizes, int n_in,
                              void* d_out, int out_size, void* d_ws, size_t ws_size,
                              hipStream_t stream) {
    const float* x_f32 = (const float*)d_in[0];
    const float* gw    = (const float*)d_in[1];
    const float* w1    = (const float*)d_in[2];
    const float* w3    = (const float*)d_in[3];
    const float* w2    = (const float*)d_in[4];
    float* out = (float*)d_out;

    char* ws = (char*)d_ws;
    int*            counts  = (int*)(ws + WS_COUNTS);
    unsigned short* work    = (unsigned short*)(ws + WS_WORK);
    int*            offsets = (int*)(ws + WS_OFFSETS);
    int*            tok     = (int*)(ws + WS_TOK);
    float*          wl      = (float*)(ws + WS_WL);
    unsigned short* X16     = (unsigned short*)(ws + WS_X16);
    unsigned short* w1t     = (unsigned short*)(ws + WS_W1T);
    float*          h2s     = (float*)(ws + WS_H2S);     // aliases w1t (dead after stage1)
    unsigned short* w3t     = (unsigned short*)(ws + WS_W3T);
    unsigned short* w2t     = (unsigned short*)(ws + WS_W2T);
    unsigned short* act     = (unsigned short*)(ws + WS_ACT);
    int*            posmap  = (int*)(ws + WS_POSMAP);

    zero_counts<<<dim3(1), 64, 0, stream>>>(counts);
    convert_x<<<dim3((T_TOK * H_DIM / 4) / 256), 256, 0, stream>>>(x_f32, X16);
    transpose_conv<<<dim3(I_DIM / 64, H_DIM / 64, E_NUM), 256, 0, stream>>>(w1, w1t, H_DIM, I_DIM);
    transpose_conv<<<dim3(I_DIM / 64, H_DIM / 64, E_NUM), 256, 0, stream>>>(w3, w3t, H_DIM, I_DIM);
    transpose_conv<<<dim3(H_DIM / 64, I_DIM / 64, E_NUM), 256, 0, stream>>>(w2, w2t, I_DIM, H_DIM);
    router<<<dim3(T_TOK), 64, 0, stream>>>(x_f32, gw, counts, tok, wl, posmap);
    prefix<<<dim3(1), 64, 0, stream>>>(counts, offsets, work);
    stage1<<<dim3(I_DIM / BN, MAXMB), 256, 0, stream>>>(
        X16, w1t, w3t, offsets, work, tok, wl, act);
    stage2<<<dim3(H_DIM / BN, MAXMB), 256, 0, stream>>>(
        act, w2t, offsets, work, h2s);
    combine<<<dim3(T_TOK, 2), 256, 0, stream>>>(h2s, posmap, offsets, out);
}